// Round 2
// baseline (814.434 us; speedup 1.0000x reference)
//
#include <hip/hip_runtime.h>
#include <hip/hip_bf16.h>

// B=4, T=256, U=128, H=512, P=512, HID=512, V=1024
// inputs: f(4,256,512) g(4,128,512) W1(1024,512) b1(512) W2(512,1024) b2(1024)
// out: (4,256,128,1024) fp32

typedef __attribute__((ext_vector_type(8)))  short          short8;
typedef __attribute__((ext_vector_type(8)))  unsigned short ushort8;
typedef __attribute__((ext_vector_type(4)))  float          f32x4;
typedef __attribute__((ext_vector_type(16))) float          f32x16;

__device__ __forceinline__ unsigned short f2bf(float x) {
    unsigned u = __builtin_bit_cast(unsigned, x);
    u += 0x7FFFu + ((u >> 16) & 1u);          // RNE
    return (unsigned short)(u >> 16);
}
__device__ __forceinline__ float bf2f(unsigned short s) {
    return __builtin_bit_cast(float, (unsigned)s << 16);
}

// ---------------------------------------------------------------------------
// Kernel 1 (merged): blocks [0,256): prepack W2 into bf16 B-fragment layout.
//                    blocks [256,448): projections.
// prep: frag (nfg in [0,32), kc in [0,32)): lane l holds
//       W2[kc*16+(l>>5)*8+j][nfg*32+(l&31)]; dst short idx = t*8+j.
// proj: blocks [256,384): hf[m,d] = f @ W1[:512] + b1  (fp32, 1024x512)
//       blocks [384,448): hg      = g @ W1[512:]       (bf16, written in
//       MFMA-A fragment layout hgpk: for (b,u,k): uc=u>>5, r=u&31, kc=k>>4,
//       lane=r+32*((k>>3)&1), j=k&7; idx=(((b*4+uc)*32+kc)*64+lane)*8+j.
//       64x64 tile/block, 4 waves (2x2), wave tile 32x32, mfma 16x16x32.
// ---------------------------------------------------------------------------
__global__ __launch_bounds__(256) void prep(const float* __restrict__ W2,
                                            unsigned short* __restrict__ W2pk,
                                            const float* __restrict__ f,
                                            const float* __restrict__ g,
                                            const float* __restrict__ W1,
                                            const float* __restrict__ b1,
                                            float* __restrict__ hf,
                                            unsigned short* __restrict__ hgpk) {
    const int bx = blockIdx.x;
    if (bx < 256) {
        // ---- W2 prepack ----
        int t   = bx * 256 + threadIdx.x;   // 65536 threads
        int l   = t & 63;
        int kc  = (t >> 6) & 31;
        int nfg = t >> 11;
        int n   = nfg * 32 + (l & 31);
        int kb  = kc * 16 + (l >> 5) * 8;
        ushort8 v;
#pragma unroll
        for (int j = 0; j < 8; ++j) v[j] = f2bf(W2[(kb + j) * 1024 + n]);
        *(ushort8*)&W2pk[(size_t)t * 8] = v;
        return;
    }
    // ---- projections ----
    const int pbx  = bx - 256;
    const bool isf = pbx < 128;
    const float* A  = isf ? f : g;
    const int w1r0  = isf ? 0 : 512;
    const int lbx   = isf ? pbx : pbx - 128;
    const int nt    = lbx & 7, mt = lbx >> 3;
    const int m0    = mt * 64, n0 = nt * 64;

    __shared__ short As[64 * 40];   // [row][k] stride 40 elems
    __shared__ short Bs[64 * 40];   // [n][k]

    const int tid = threadIdx.x, lane = tid & 63, wave = tid >> 6;
    const int wm = wave & 1, wn = wave >> 1;

    f32x4 acc[2][2] = {};

    for (int k0 = 0; k0 < 512; k0 += 32) {
        // stage A (64 rows x 32 k), fp32 -> bf16
        {
            int row = tid & 63, kq = tid >> 6;
            const float* src = A + (size_t)(m0 + row) * 512 + k0 + kq * 8;
            f32x4 v0 = *(const f32x4*)src;
            f32x4 v1 = *(const f32x4*)(src + 4);
            short8 p;
#pragma unroll
            for (int j = 0; j < 4; ++j) p[j]     = (short)f2bf(v0[j]);
#pragma unroll
            for (int j = 0; j < 4; ++j) p[4 + j] = (short)f2bf(v1[j]);
            *(short8*)&As[row * 40 + kq * 8] = p;
        }
        // stage B transposed: Bs[n][k] = W1[w1r0+k0+k][n0+n]
        {
            int n = tid & 63, kq = tid >> 6;
#pragma unroll
            for (int i = 0; i < 8; ++i) {
                int k = kq * 8 + i;
                Bs[n * 40 + k] = (short)f2bf(W1[(size_t)(w1r0 + k0 + k) * 512 + n0 + n]);
            }
        }
        __syncthreads();
        {
            const int q16 = (lane >> 4) * 8, l16 = lane & 15;
            short8 a0 = *(const short8*)&As[(wm * 32 +      l16) * 40 + q16];
            short8 a1 = *(const short8*)&As[(wm * 32 + 16 + l16) * 40 + q16];
            short8 b0 = *(const short8*)&Bs[(wn * 32 +      l16) * 40 + q16];
            short8 b1f= *(const short8*)&Bs[(wn * 32 + 16 + l16) * 40 + q16];
            acc[0][0] = __builtin_amdgcn_mfma_f32_16x16x32_bf16(a0, b0,  acc[0][0], 0, 0, 0);
            acc[0][1] = __builtin_amdgcn_mfma_f32_16x16x32_bf16(a0, b1f, acc[0][1], 0, 0, 0);
            acc[1][0] = __builtin_amdgcn_mfma_f32_16x16x32_bf16(a1, b0,  acc[1][0], 0, 0, 0);
            acc[1][1] = __builtin_amdgcn_mfma_f32_16x16x32_bf16(a1, b1f, acc[1][1], 0, 0, 0);
        }
        __syncthreads();
    }

    // epilogue: C/D 16x16: col=lane&15, row=(lane>>4)*4+reg
#pragma unroll
    for (int nf = 0; nf < 2; ++nf) {
        int col = n0 + wn * 32 + nf * 16 + (lane & 15);
        float bv = isf ? b1[col] : 0.0f;
#pragma unroll
        for (int mf = 0; mf < 2; ++mf) {
#pragma unroll
            for (int r = 0; r < 4; ++r) {
                int row = m0 + wm * 32 + mf * 16 + (lane >> 4) * 4 + r;
                float v = acc[mf][nf][r] + bv;
                if (isf) {
                    hf[(size_t)row * 512 + col] = v;
                } else {
                    // hg in MFMA-A fragment layout (see header comment)
                    int b_  = row >> 7, u = row & 127;
                    int uc  = u >> 5,   rr = u & 31;
                    int kc2 = col >> 4, kk = col & 15;
                    int ln  = rr + 32 * (kk >> 3), j = kk & 7;
                    size_t idx = ((((size_t)b_ * 4 + uc) * 32 + kc2) * 64 + ln) * 8 + j;
                    hgpk[idx] = f2bf(v);
                }
            }
        }
    }
}

// ---------------------------------------------------------------------------
// Kernel 2: joint — ZERO LDS, ZERO barriers. grid 4096, 4 waves (2m x 2n),
// block tile 128x256, wave tile 64x128, mfma 32x32x16 bf16.
// Each wave builds its A fragments in registers: for chunk kc, m-half mh,
// lane l computes tanh(hf[k] + hg[u][k]) for u = (wm*2+mh)*32 + (l&31),
// k = kc*16 + (l>>5)*8 + j — hg comes pre-packed in exactly this fragment
// layout (coalesced ushort8 loads), B frags from prepacked W2pk.  Waves run
// fully independently; MFMA (matrix pipe) overlaps tanh (VALU) and VMEM
// across the 2 resident waves/SIMD.  XCD-bijective swizzle clusters one nt
// (256-col W2pk slice, 256 KiB) per XCD for L2/L1 reuse.
// ---------------------------------------------------------------------------
__global__ __launch_bounds__(256, 2) void joint(const float* __restrict__ hf,
                                                const unsigned short* __restrict__ hgpk,
                                                const short8* __restrict__ W2pk,
                                                const float* __restrict__ b2,
                                                float* __restrict__ out) {
    // XCD swizzle: 4096 blocks, 8 XCDs -> 512 contiguous per XCD, nt = chunk>>10
    const int bid   = blockIdx.x;
    const int swz   = (bid & 7) * 512 + (bid >> 3);
    const int nt    = swz >> 10;
    const int mtile = swz & 1023;                   // = b*256 + t
    const float* hf_row = hf + (size_t)mtile * 512;
    const int b_idx = mtile >> 8;
    const short8* hgf = (const short8*)hgpk + (size_t)b_idx * (4 * 32 * 64);

    const int tid = threadIdx.x, lane = tid & 63, wave = tid >> 6;
    const int wm = wave & 1, wn = wave >> 1;
    const int lh = lane >> 5;

    f32x16 acc[2][4] = {};

    for (int step = 0; step < 8; ++step) {
        const int k0 = step * 64;
#pragma unroll
        for (int c = 0; c < 4; ++c) {
            const int kc = step * 4 + c;
            // hf slice for this chunk: k = k0 + c*16 + lh*8 + j  (half-wave broadcast)
            const float* hp = hf_row + k0 + c * 16 + lh * 8;
            f32x4 hfa = *(const f32x4*)hp;
            f32x4 hfb = *(const f32x4*)(hp + 4);
            // build A fragments in registers (one per m-half)
            short8 a[2];
#pragma unroll
            for (int mh = 0; mh < 2; ++mh) {
                const int uc = wm * 2 + mh;
                ushort8 hv = __builtin_bit_cast(ushort8,
                    hgf[(size_t)((uc * 32 + kc) * 64 + lane)]);
                short8 pck;
#pragma unroll
                for (int j = 0; j < 8; ++j) {
                    float x   = ((j < 4) ? hfa[j] : hfb[j - 4]) + bf2f(hv[j]);
                    float tnh = x * __builtin_amdgcn_rcpf(1.0f + __builtin_fabsf(x));
                    pck[j] = (short)f2bf(tnh);
                }
                a[mh] = pck;
            }
            // MFMA cluster
            __builtin_amdgcn_s_setprio(1);
#pragma unroll
            for (int nf = 0; nf < 4; ++nf) {
                const int nfg = nt * 8 + wn * 4 + nf;
                short8 bfrag = W2pk[(size_t)(nfg * 32 + kc) * 64 + lane];
                acc[0][nf] = __builtin_amdgcn_mfma_f32_32x32x16_bf16(a[0], bfrag, acc[0][nf], 0, 0, 0);
                acc[1][nf] = __builtin_amdgcn_mfma_f32_32x32x16_bf16(a[1], bfrag, acc[1][nf], 0, 0, 0);
            }
            __builtin_amdgcn_s_setprio(0);
        }
    }

    // ---- epilogue: C/D 32x32: col=lane&31, row=(reg&3)+8*(reg>>2)+4*(lane>>5) ----
    float* outb = out + (size_t)mtile * 128 * 1024 + nt * 256;
    const int cl = lane & 31, rq = (lane >> 5) * 4;
#pragma unroll
    for (int nf = 0; nf < 4; ++nf) {
        int col  = wn * 128 + nf * 32 + cl;
        float bv = b2[nt * 256 + col];
#pragma unroll
        for (int mf = 0; mf < 2; ++mf) {
#pragma unroll
            for (int reg = 0; reg < 16; ++reg) {
                int row = wm * 64 + mf * 32 + (reg & 3) + 8 * (reg >> 2) + rq;
                outb[(size_t)row * 1024 + col] = acc[mf][nf][reg] + bv;
            }
        }
    }
}

// ---------------------------------------------------------------------------
extern "C" void kernel_launch(void* const* d_in, const int* in_sizes, int n_in,
                              void* d_out, int out_size, void* d_ws, size_t ws_size,
                              hipStream_t stream) {
    const float* f  = (const float*)d_in[0];
    const float* g  = (const float*)d_in[1];
    const float* W1 = (const float*)d_in[2];
    const float* b1 = (const float*)d_in[3];
    const float* W2 = (const float*)d_in[4];
    const float* b2 = (const float*)d_in[5];
    float* out = (float*)d_out;

    char* ws = (char*)d_ws;
    unsigned short* W2pk = (unsigned short*)ws;                      // 1 MB
    float*          hf   = (float*)(ws + (1u << 20));                // 2 MB
    unsigned short* hgpk = (unsigned short*)(ws + 3u * (1u << 20));  // 512 KB

    prep<<<448, 256, 0, stream>>>(W2, W2pk, f, g, W1, b1, hf, hgpk);
    joint<<<4096, 256, 0, stream>>>(hf, hgpk, (const short8*)W2pk, b2, out);
}